// Round 1
// baseline (69.082 us; speedup 1.0000x reference)
//
#include <hip/hip_runtime.h>

#define RADIUS 5
#define TILEX  32                   // output px per block in x
#define TILEY  16                   // output px per block in y
#define HX     (TILEX + 2*RADIUS)   // 42
#define HY     (TILEY + 2*RADIUS)   // 26
#define HPITCH 23                   // float4 pitch: row shift 92 words = 28 mod 32
                                    // -> h rows hit bank starts {0,28,24,20}: alternating
                                    //    mod-8 halves, uniform 8B/bank per 16-lane phase
#define EO     (HY * HPITCH)        // 598 float4s: odd-parity offset inside each array
#define H      256
#define W      256

// exp2-folded Mahalanobis coefficients kappa = -0.5*log2(e)*sigma_inv:
// ch0-1 (sigma 10.0), ch2-4 (0.02), ch5-7 (0.1)
#define KA (-0.072134752f)
#define KB (-36.06737602f)
#define KC (-7.213475204f)

typedef float v2f __attribute__((ext_vector_type(2)));

struct Center { v2f h01, h23, h45, h67; float phic; };

// Quadratic expansion, packed-fp32 form: t = P.w + pg + sum h_i*g_i computed as
// 4 v_pk_fma_f32 + adds; accumulates as 2 v_pk_fma_f32. pg carries the row/parity
// gate bias (-1000 -> exp2 = +0.0 exactly, so gated accums are exact no-ops).
__device__ __forceinline__ void accum(const float4 A, const float4 G, const float4 P,
                                      const Center& C, const float pg,
                                      v2f& swx, v2f& syz) {
    v2f t2;  t2.x = P.w + pg; t2.y = 0.f;
    v2f a01; a01.x = A.x; a01.y = A.y;
    v2f a23; a23.x = A.z; a23.y = A.w;
    v2f g01; g01.x = G.x; g01.y = G.y;
    v2f g23; g23.x = G.z; g23.y = G.w;
    t2 = __builtin_elementwise_fma(C.h01, a01, t2);
    t2 = __builtin_elementwise_fma(C.h23, a23, t2);
    t2 = __builtin_elementwise_fma(C.h45, g01, t2);
    t2 = __builtin_elementwise_fma(C.h67, g23, t2);
    const float w = __builtin_amdgcn_exp2f(t2.x + t2.y);
    v2f w2;  w2.x = w;   w2.y = w;
    v2f m0;  m0.x = 1.f; m0.y = P.x;
    v2f m1;  m1.x = P.y; m1.y = P.z;
    swx = __builtin_elementwise_fma(w2, m0, swx);   // (sum_w, acc_x)
    syz = __builtin_elementwise_fma(w2, m1, syz);   // (acc_y, acc_z)
}

// R14 = R13 + 4x2-center threads with even/odd parity split over lane bit 5.
// R13 was LDS-read-bound: 108 ds_read_b128/thread for 132 accums (2x2 centers,
// ~1.2 accums per float4 triple). R14: each (txp,typ) owns 4x2 output px; the
// 14-column window = 7 even + 7 odd pairs is split by lane bit 5 (ks): even
// half-wave reads only e-arrays, odd half-wave only o-arrays -> 63 loop reads
// per thread (-42%) at the same wave count / grid / staging. Parity-asymmetric
// column gates (4 of 24 (k,cx) combos) fold into the exp2 bias like row gates.
// Partials combine over lane bits 3,4 (h: shfl_xor 8,16) and 5 (ks: shfl_xor 32).
// block (8,8,8): txp = px-quad x (lane bits 0-2), hy = h|ks<<2 (bits 3-5),
// typ = y-quad (wave id). 4x2 px per thread.
__global__ __launch_bounds__(512, 2) void jbf_kernel(
    const float* __restrict__ image,     // (B,3,H,W)
    const float* __restrict__ guidance,  // (B,8,H,W)
    float* __restrict__ out)             // (B,3,H,W)
{
    // [0..EO) even column-pairs, [EO..2*EO) odd column-pairs
    __shared__ float4 g0[2 * EO];   // guidance ch0-3
    __shared__ float4 g1[2 * EO];   // guidance ch4-7
    __shared__ float4 im[2 * EO];   // image ch0-2 + phi

    // XCD swizzle: c = id%8 (XCD), r = id/8 (rank within XCD).
    // XCDs 0-3 -> batch 0, 4-7 -> batch 1; XCD owns tile-cols {2m, 2m+1}
    // (m = c%4) over all 16 tile-rows: bx = 2m + (r&1), by = r>>1.
    const int id = blockIdx.x;
    const int c_xcd = id & 7;
    const int r_rnk = id >> 3;               // 0..31
    const int b       = c_xcd >> 2;
    const int tile_x0 = (((c_xcd & 3) << 1) | (r_rnk & 1)) * TILEX;
    const int tile_y0 = (r_rnk >> 1) * TILEY;

    const int txp = threadIdx.x;             // 0..7  (lane bits 0-2)
    const int hy  = threadIdx.y;             // 0..7  (lane bits 3-5)
    const int h   = hy & 3;                  // row quarter
    const int ks  = hy >> 2;                 // column parity: 0=even, 1=odd
    const int typ = threadIdx.z;             // 0..7  (wave id)
    const int tid = (typ * 8 + hy) * 8 + txp;

    const float* gbase = guidance + (size_t)b * 8 * H * W;
    const float* ibase = image    + (size_t)b * 3 * H * W;

    // ---- stage 42x26 halo (reflect) into even/odd interleaved LDS ----
    for (int idx = tid; idx < HX * HY; idx += 512) {
        const int ly = idx / HX;
        const int lx = idx - ly * HX;
        int gy = tile_y0 - RADIUS + ly;
        int gx = tile_x0 - RADIUS + lx;
        gy = (gy < 0) ? -gy : ((gy >= H) ? 2 * (H - 1) - gy : gy);
        gx = (gx < 0) ? -gx : ((gx >= W) ? 2 * (W - 1) - gx : gx);
        const int off = gy * W + gx;
        const int l   = ly * HPITCH + (lx >> 1) + ((lx & 1) ? EO : 0);
        const float4 v0 = make_float4(gbase[0*H*W+off], gbase[1*H*W+off],
                                      gbase[2*H*W+off], gbase[3*H*W+off]);
        const float4 v1 = make_float4(gbase[4*H*W+off], gbase[5*H*W+off],
                                      gbase[6*H*W+off], gbase[7*H*W+off]);
        const float phi = KA * (v0.x*v0.x + v0.y*v0.y)
                        + KB * (v0.z*v0.z + v0.w*v0.w + v1.x*v1.x)
                        + KC * (v1.y*v1.y + v1.z*v1.z + v1.w*v1.w);
        const float4 vi = make_float4(ibase[0*H*W+off], ibase[1*H*W+off],
                                      ibase[2*H*W+off], phi);
        g0[l] = v0; g1[l] = v1; im[l] = vi;
    }
    __syncthreads();

    // centers cx=0..3 at halo cols 4txp+5+cx -> pair idx 2txp+{2,3,3,4},
    // parity {odd,even,odd,even}; rows 2typ+5+cy
    Center c[4][2];
    #pragma unroll
    for (int cy = 0; cy < 2; ++cy) {
        const int row = (2 * typ + 5 + cy) * HPITCH + 2 * txp;
        const int ci[4] = { row + 2 + EO, row + 3, row + 3 + EO, row + 4 };
        #pragma unroll
        for (int cx = 0; cx < 4; ++cx) {
            const float4 gA = g0[ci[cx]];
            const float4 gB = g1[ci[cx]];
            const float4 pv = im[ci[cx]];
            c[cx][cy].h01.x = -2.f*KA*gA.x;  c[cx][cy].h01.y = -2.f*KA*gA.y;
            c[cx][cy].h23.x = -2.f*KB*gA.z;  c[cx][cy].h23.y = -2.f*KB*gA.w;
            c[cx][cy].h45.x = -2.f*KB*gB.x;  c[cx][cy].h45.y = -2.f*KC*gB.y;
            c[cx][cy].h67.x = -2.f*KC*gB.z;  c[cx][cy].h67.y = -2.f*KC*gB.w;
            c[cx][cy].phic  = pv.w;
        }
    }

    v2f swx[4][2], syz[4][2];
    #pragma unroll
    for (int cx = 0; cx < 4; ++cx)
        #pragma unroll
        for (int cy = 0; cy < 2; ++cy) {
            swx[cx][cy].x = 0.f; swx[cx][cy].y = 0.f;
            syz[cx][cy].x = 0.f; syz[cx][cy].y = 0.f;
        }

    // Parity gate biases: each cx has exactly one k where only one parity is
    // in-window (cx0@k5, cx2@k6: even only; cx1@k0, cx3@k1: odd only).
    const float bE = ks ? -1000.f : 0.f;    // keep even-parity lanes only
    const float bO = ks ? 0.f : -1000.f;    // keep odd-parity lanes only
    const int   pb = ks * EO;               // parity-selected array half

    // quarter h handles halo rows r = h, h+4, h+8 of the quad's 12-row union.
    // Row-gate folded into exp2 arg: pg = phic + (serves ? 0 : -1000).
    #pragma unroll
    for (int i = 0; i < 3; ++i) {
        const int r  = 4 * i + h;
        const int rb = (2 * typ + r) * HPITCH + 2 * txp + pb;
        const float b0 = (r <= 10) ? 0.0f : -1000.0f;   // serves y0?
        const float b1 = (r >= 1)  ? 0.0f : -1000.0f;   // serves y1?
        float pgp[4][2], pgb[4][2];
        #pragma unroll
        for (int cx = 0; cx < 4; ++cx) {
            pgp[cx][0] = c[cx][0].phic + b0;
            pgp[cx][1] = c[cx][1].phic + b1;
            const float bx = (cx & 1) ? bO : bE;
            pgb[cx][0] = pgp[cx][0] + bx;
            pgb[cx][1] = pgp[cx][1] + bx;
        }
        #define ACCP(cx) do { \
            accum(A, G, P, c[cx][0], pgp[cx][0], swx[cx][0], syz[cx][0]); \
            accum(A, G, P, c[cx][1], pgp[cx][1], swx[cx][1], syz[cx][1]); } while (0)
        #define ACCB(cx) do { \
            accum(A, G, P, c[cx][0], pgb[cx][0], swx[cx][0], syz[cx][0]); \
            accum(A, G, P, c[cx][1], pgb[cx][1], swx[cx][1], syz[cx][1]); } while (0)
        // per-parity k windows (pair idx k covers cols 4txp+2k(+ks)):
        //   even: cx0 [0,5] cx1 [1,5] cx2 [1,6] cx3 [2,6]
        //   odd:  cx0 [0,4] cx1 [0,5] cx2 [1,5] cx3 [1,6]
        #pragma unroll
        for (int k = 0; k < 7; ++k) {
            const float4 A = g0[rb + k], G = g1[rb + k], P = im[rb + k];
            if (k == 0)      { ACCP(0); ACCB(1); }
            else if (k == 1) { ACCP(0); ACCP(1); ACCP(2); ACCB(3); }
            else if (k <= 4) { ACCP(0); ACCP(1); ACCP(2); ACCP(3); }
            else if (k == 5) { ACCB(0); ACCP(1); ACCP(2); ACCP(3); }
            else             { ACCB(2); ACCP(3); }
        }
        #undef ACCP
        #undef ACCB
    }

    // combine partials: butterfly over lane bits 3,4 (h) and 5 (parity)
    #define RED(v) do { v += __shfl_xor(v, 8); v += __shfl_xor(v, 16); \
                        v += __shfl_xor(v, 32); } while (0)
    #pragma unroll
    for (int cx = 0; cx < 4; ++cx)
        #pragma unroll
        for (int cy = 0; cy < 2; ++cy) {
            RED(swx[cx][cy].x);  RED(swx[cx][cy].y);
            RED(syz[cx][cy].x);  RED(syz[cx][cy].y);
        }
    #undef RED

    if (hy == 0) {
        // sum_w >= ~1 (center weight ~ 1); reference clip(1e-10) is a no-op
        const size_t base = (size_t)b * 3 * H * W
                          + (size_t)(tile_y0 + 2 * typ) * W + (tile_x0 + 4 * txp);
        #pragma unroll
        for (int cy = 0; cy < 2; ++cy) {
            float inv[4];
            #pragma unroll
            for (int cx = 0; cx < 4; ++cx) inv[cx] = 1.0f / swx[cx][cy].x;
            float4* __restrict__ o4 = (float4*)(out + base + (size_t)cy * W);
            o4[0]             = make_float4(swx[0][cy].y*inv[0], swx[1][cy].y*inv[1],
                                            swx[2][cy].y*inv[2], swx[3][cy].y*inv[3]);
            o4[(H*W) / 4]     = make_float4(syz[0][cy].x*inv[0], syz[1][cy].x*inv[1],
                                            syz[2][cy].x*inv[2], syz[3][cy].x*inv[3]);
            o4[(2*H*W) / 4]   = make_float4(syz[0][cy].y*inv[0], syz[1][cy].y*inv[1],
                                            syz[2][cy].y*inv[2], syz[3][cy].y*inv[3]);
        }
    }
}

extern "C" void kernel_launch(void* const* d_in, const int* in_sizes, int n_in,
                              void* d_out, int out_size, void* d_ws, size_t ws_size,
                              hipStream_t stream) {
    const float* image    = (const float*)d_in[0];
    const float* guidance = (const float*)d_in[1];
    float* out            = (float*)d_out;

    // flat grid: in-kernel XCD swizzle maps id -> (batch, tile). 256 = 8x16x2.
    dim3 grid(256, 1, 1);
    dim3 block(8, 8, 8);                       // 512 threads = 8 waves
    hipLaunchKernelGGL(jbf_kernel, grid, block, 0, stream, image, guidance, out);
}

// Round 4
// 66.731 us; speedup vs baseline: 1.0352x; 1.0352x over previous
//
#include <hip/hip_runtime.h>

#define RADIUS 5
#define TILEX  32                   // output px per block in x
#define TILEY  16                   // output px per block in y
#define HX     (TILEX + 2*RADIUS)   // 42
#define HY     (TILEY + 2*RADIUS)   // 26
#define HPITCH 22                   // half-col pitch: row shift 88 words = 24 mod 32
                                    // -> h-quarter rows hit bank starts {0,24,16,8} (uniform)
#define H      256
#define W      256

// exp2-folded Mahalanobis coefficients kappa = -0.5*log2(e)*sigma_inv:
// ch0-1 (sigma 10.0), ch2-4 (0.02), ch5-7 (0.1)
#define KA (-0.072134752f)
#define KB (-36.06737602f)
#define KC (-7.213475204f)

typedef float v2f __attribute__((ext_vector_type(2)));

struct Center { v2f h01, h23, h45, h67; float phic; };

// Quadratic expansion, packed-fp32 form: t = P.w + pg + sum h_i*g_i computed as
// 4 v_pk_fma_f32 + adds; accumulates as 2 v_pk_fma_f32. pg carries the row-gate
// bias (-1000 -> exp2 = +0.0 exactly, so gated accums are exact no-ops).
__device__ __forceinline__ void accum(const float4 A, const float4 G, const float4 P,
                                      const Center& C, const float pg,
                                      v2f& swx, v2f& syz) {
    v2f t2;  t2.x = P.w + pg; t2.y = 0.f;
    v2f a01; a01.x = A.x; a01.y = A.y;
    v2f a23; a23.x = A.z; a23.y = A.w;
    v2f g01; g01.x = G.x; g01.y = G.y;
    v2f g23; g23.x = G.z; g23.y = G.w;
    t2 = __builtin_elementwise_fma(C.h01, a01, t2);
    t2 = __builtin_elementwise_fma(C.h23, a23, t2);
    t2 = __builtin_elementwise_fma(C.h45, g01, t2);
    t2 = __builtin_elementwise_fma(C.h67, g23, t2);
    const float w = __builtin_amdgcn_exp2f(t2.x + t2.y);
    v2f w2;  w2.x = w;   w2.y = w;
    v2f m0;  m0.x = 1.f; m0.y = P.x;
    v2f m1;  m1.x = P.y; m1.y = P.z;
    swx = __builtin_elementwise_fma(w2, m0, swx);   // (sum_w, acc_x)
    syz = __builtin_elementwise_fma(w2, m1, syz);   // (acc_y, acc_z)
}

// R17 = R13 (best verified, 66.9us) with __launch_bounds__(512, 1).
// Rationale: grid is 256 blocks on 256 CUs -> exactly 1 block/CU at runtime,
// but launch_bounds(512,2) capped the allocator at 128 VGPR (4 waves/SIMD) for
// a second resident block that never exists. R13's live set (4 Centers = 36 +
// 8 v2f accums = 16 + 12 in-flight float4 LDS loads = 48 + addr/staging temps)
// sits right at that cap -> spills / restricted ds_read look-ahead. (512,1)
// unlocks 256 VGPR with zero occupancy change by construction.
// R14-R16 post-mortem: the 4x2-center parity-split branch is EV-negative —
// its Center[4][2] = 72 VGPR guarantees pressure, R14 measured +2.2us, and a
// working DS-light reduction still projects worse than R13. Abandoned.
// block (16,4,8): txp = px-pair x (lane bits 0-3), h = row-quarter (lane bits
// 4-5 -> shfl_xor(16/32) combine), typ = y-quad (wave id). 2x2 px per thread.
__global__ __launch_bounds__(512, 1) void jbf_kernel(
    const float* __restrict__ image,     // (B,3,H,W)
    const float* __restrict__ guidance,  // (B,8,H,W)
    float* __restrict__ out)             // (B,3,H,W)
{
    __shared__ float4 g0e[HY * HPITCH], g0o[HY * HPITCH];  // guidance ch0-3
    __shared__ float4 g1e[HY * HPITCH], g1o[HY * HPITCH];  // guidance ch4-7
    __shared__ float4 ime[HY * HPITCH], imo[HY * HPITCH];  // image ch0-2 + phi

    // XCD swizzle: c = id%8 (XCD), r = id/8 (rank within XCD).
    // XCDs 0-3 -> batch 0, 4-7 -> batch 1; XCD owns tile-cols {2m, 2m+1}
    // (m = c%4) over all 16 tile-rows: bx = 2m + (r&1), by = r>>1.
    const int id = blockIdx.x;
    const int c_xcd = id & 7;
    const int r_rnk = id >> 3;               // 0..31
    const int b       = c_xcd >> 2;
    const int tile_x0 = (((c_xcd & 3) << 1) | (r_rnk & 1)) * TILEX;
    const int tile_y0 = (r_rnk >> 1) * TILEY;

    const int txp = threadIdx.x;             // 0..15 (lane bits 0-3)
    const int h   = threadIdx.y;             // 0..3  (lane bits 4-5)
    const int typ = threadIdx.z;             // 0..7  (wave id)
    const int tid = (typ * 4 + h) * 16 + txp;

    const float* gbase = guidance + (size_t)b * 8 * H * W;
    const float* ibase = image    + (size_t)b * 3 * H * W;

    // ---- stage 42x26 halo (reflect) into even/odd interleaved LDS ----
    for (int idx = tid; idx < HX * HY; idx += 512) {
        const int ly = idx / HX;
        const int lx = idx - ly * HX;
        int gy = tile_y0 - RADIUS + ly;
        int gx = tile_x0 - RADIUS + lx;
        gy = (gy < 0) ? -gy : ((gy >= H) ? 2 * (H - 1) - gy : gy);
        gx = (gx < 0) ? -gx : ((gx >= W) ? 2 * (W - 1) - gx : gx);
        const int off = gy * W + gx;
        const int l   = ly * HPITCH + (lx >> 1);
        const float4 v0 = make_float4(gbase[0*H*W+off], gbase[1*H*W+off],
                                      gbase[2*H*W+off], gbase[3*H*W+off]);
        const float4 v1 = make_float4(gbase[4*H*W+off], gbase[5*H*W+off],
                                      gbase[6*H*W+off], gbase[7*H*W+off]);
        const float phi = KA * (v0.x*v0.x + v0.y*v0.y)
                        + KB * (v0.z*v0.z + v0.w*v0.w + v1.x*v1.x)
                        + KC * (v1.y*v1.y + v1.z*v1.z + v1.w*v1.w);
        const float4 vi = make_float4(ibase[0*H*W+off], ibase[1*H*W+off],
                                      ibase[2*H*W+off], phi);
        if (lx & 1) { g0o[l] = v0; g1o[l] = v1; imo[l] = vi; }
        else        { g0e[l] = v0; g1e[l] = v1; ime[l] = vi; }
    }
    __syncthreads();

    // centers: x0 = halo col 2txp+5 (odd, idx txp+2), x1 = 2txp+6 (even, txp+3)
    //          y0 = halo row 2typ+5, y1 = 2typ+6
    Center c[2][2];
    #pragma unroll
    for (int cy = 0; cy < 2; ++cy) {
        const int row = (2 * typ + 5 + cy) * HPITCH;
        #pragma unroll
        for (int cx = 0; cx < 2; ++cx) {
            const int ci = row + txp + 2 + cx;
            const float4 gA = cx ? g0e[ci] : g0o[ci];
            const float4 gB = cx ? g1e[ci] : g1o[ci];
            const float4 pv = cx ? ime[ci] : imo[ci];
            c[cx][cy].h01.x = -2.f*KA*gA.x;  c[cx][cy].h01.y = -2.f*KA*gA.y;
            c[cx][cy].h23.x = -2.f*KB*gA.z;  c[cx][cy].h23.y = -2.f*KB*gA.w;
            c[cx][cy].h45.x = -2.f*KB*gB.x;  c[cx][cy].h45.y = -2.f*KC*gB.y;
            c[cx][cy].h67.x = -2.f*KC*gB.z;  c[cx][cy].h67.y = -2.f*KC*gB.w;
            c[cx][cy].phic  = pv.w;
        }
    }

    v2f swx[2][2], syz[2][2];
    #pragma unroll
    for (int cx = 0; cx < 2; ++cx)
        #pragma unroll
        for (int cy = 0; cy < 2; ++cy) {
            swx[cx][cy].x = 0.f; swx[cx][cy].y = 0.f;
            syz[cx][cy].x = 0.f; syz[cx][cy].y = 0.f;
        }

    // quarter h handles halo rows r = h, h+4, h+8 of the quad's 12-row union.
    // Row-gate folded into exp2 arg: pg = phic + (serves ? 0 : -1000).
    #pragma unroll
    for (int i = 0; i < 3; ++i) {
        const int r  = 4 * i + h;
        const int rb = (2 * typ + r) * HPITCH + txp;
        const float b0 = (r <= 10) ? 0.0f : -1000.0f;   // serves y0?
        const float b1 = (r >= 1)  ? 0.0f : -1000.0f;   // serves y1?
        const float pg00 = c[0][0].phic + b0, pg01 = c[0][1].phic + b1;
        const float pg10 = c[1][0].phic + b0, pg11 = c[1][1].phic + b1;
        #pragma unroll
        for (int k = 0; k <= 5; ++k) {
            {   // EVEN columns: serve x0 (all k), x1 (k>=1)
                const float4 A = g0e[rb + k], G = g1e[rb + k], P = ime[rb + k];
                accum(A, G, P, c[0][0], pg00, swx[0][0], syz[0][0]);
                accum(A, G, P, c[0][1], pg01, swx[0][1], syz[0][1]);
                if (k >= 1) {
                    accum(A, G, P, c[1][0], pg10, swx[1][0], syz[1][0]);
                    accum(A, G, P, c[1][1], pg11, swx[1][1], syz[1][1]);
                }
            }
            {   // ODD columns: serve x0 (k<=4), x1 (all k)
                const float4 A = g0o[rb + k], G = g1o[rb + k], P = imo[rb + k];
                if (k <= 4) {
                    accum(A, G, P, c[0][0], pg00, swx[0][0], syz[0][0]);
                    accum(A, G, P, c[0][1], pg01, swx[0][1], syz[0][1]);
                }
                accum(A, G, P, c[1][0], pg10, swx[1][0], syz[1][0]);
                accum(A, G, P, c[1][1], pg11, swx[1][1], syz[1][1]);
            }
        }
    }

    // combine row-quarter partials: butterfly over lane bits 4-5 (h)
    #pragma unroll
    for (int cx = 0; cx < 2; ++cx)
        #pragma unroll
        for (int cy = 0; cy < 2; ++cy) {
            swx[cx][cy].x += __shfl_xor(swx[cx][cy].x, 16);
            swx[cx][cy].x += __shfl_xor(swx[cx][cy].x, 32);
            swx[cx][cy].y += __shfl_xor(swx[cx][cy].y, 16);
            swx[cx][cy].y += __shfl_xor(swx[cx][cy].y, 32);
            syz[cx][cy].x += __shfl_xor(syz[cx][cy].x, 16);
            syz[cx][cy].x += __shfl_xor(syz[cx][cy].x, 32);
            syz[cx][cy].y += __shfl_xor(syz[cx][cy].y, 16);
            syz[cx][cy].y += __shfl_xor(syz[cx][cy].y, 32);
        }

    if (h == 0) {
        // sum_w >= ~1 (center weight ~ 1); reference clip(1e-10) is a no-op
        const size_t base = (size_t)b * 3 * H * W
                          + (size_t)(tile_y0 + 2 * typ) * W + (tile_x0 + 2 * txp);
        #pragma unroll
        for (int cy = 0; cy < 2; ++cy) {
            const float i0 = 1.0f / swx[0][cy].x;
            const float i1 = 1.0f / swx[1][cy].x;
            float2* __restrict__ o2 = (float2*)(out + base + (size_t)cy * W);
            o2[0]           = make_float2(swx[0][cy].y * i0, swx[1][cy].y * i1);
            o2[(H*W) / 2]   = make_float2(syz[0][cy].x * i0, syz[1][cy].x * i1);
            o2[(2*H*W) / 2] = make_float2(syz[0][cy].y * i0, syz[1][cy].y * i1);
        }
    }
}

extern "C" void kernel_launch(void* const* d_in, const int* in_sizes, int n_in,
                              void* d_out, int out_size, void* d_ws, size_t ws_size,
                              hipStream_t stream) {
    const float* image    = (const float*)d_in[0];
    const float* guidance = (const float*)d_in[1];
    float* out            = (float*)d_out;

    // flat grid: in-kernel XCD swizzle maps id -> (batch, tile). 256 = 8x16x2.
    dim3 grid(256, 1, 1);
    dim3 block(16, 4, 8);                      // 512 threads = 8 waves
    hipLaunchKernelGGL(jbf_kernel, grid, block, 0, stream, image, guidance, out);
}